// Round 5
// baseline (372.288 us; speedup 1.0000x reference)
//
#include <hip/hip_runtime.h>
#include <hip/hip_bf16.h>

#define DIMK 512
#define NROWS 131072

typedef __bf16 bf16x8 __attribute__((ext_vector_type(8)));
typedef float f32x4 __attribute__((ext_vector_type(4)));

// W in MFMA-fragment order: [colblk(32)][kblk(64)][l15(16)][8 k] bf16
__device__ __attribute__((aligned(16))) unsigned short g_Wt2[DIMK * DIMK];
__device__ int g_rows[NROWS];   // [0..nmask) masked; [NROWS-ncopy..NROWS) copy (reversed)
__device__ int g_cnt[2];        // [0]=nmask [1]=ncopy

static __device__ __forceinline__ void gload_lds16(const float* g, float* l) {
    __builtin_amdgcn_global_load_lds(
        (const __attribute__((address_space(1))) void*)(unsigned long)(g),
        (__attribute__((address_space(3))) void*)(unsigned long)(l), 16, 0, 0);
}

// ---------- W[k][n] fp32 -> fragment-ordered bf16 (also resets g_cnt) ----------
__global__ void wprep_kernel(const float* __restrict__ W) {
    if (blockIdx.x == 0 && threadIdx.x == 0) { g_cnt[0] = 0; g_cnt[1] = 0; }
    __shared__ float tile[64][65];
    const int bk = blockIdx.x & 7;
    const int bn = blockIdx.x >> 3;
    const int t = threadIdx.x;       // 256
    const int rl = t >> 2;
    const int ch = t & 3;

    const float* src = W + (bk * 64 + rl) * DIMK + bn * 64 + ch * 16;
    float4 v[4];
#pragma unroll
    for (int i = 0; i < 4; i++) v[i] = reinterpret_cast<const float4*>(src)[i];
#pragma unroll
    for (int i = 0; i < 4; i++) {
        tile[rl][ch * 16 + i * 4 + 0] = v[i].x;
        tile[rl][ch * 16 + i * 4 + 1] = v[i].y;
        tile[rl][ch * 16 + i * 4 + 2] = v[i].z;
        tile[rl][ch * 16 + i * 4 + 3] = v[i].w;
    }
    __syncthreads();

    unsigned short o[16];
#pragma unroll
    for (int i = 0; i < 16; i++) {
        float f = tile[ch * 16 + i][rl];
        unsigned u = __builtin_bit_cast(unsigned, f);
        u += 0x7FFFu + ((u >> 16) & 1u);
        o[i] = (unsigned short)(u >> 16);
    }
    const int colblk = bn * 4 + (rl >> 4);
    const int kblk = bk * 8 + ch * 2;
    unsigned short* dst = g_Wt2 + colblk * 8192 + kblk * 128 + (rl & 15) * 8;
    *reinterpret_cast<uint4*>(dst) = *reinterpret_cast<uint4*>(&o[0]);
    *reinterpret_cast<uint4*>(dst + 128) = *reinterpret_cast<uint4*>(&o[8]);
}

// ---------- fused dtype-detect + stream compaction ----------
__global__ void partition_kernel(const void* __restrict__ maskp) {
    __shared__ int s_flags;  // bit0: bad word (=> byte mask), bit1: odd-word nonzero (=> int32)
    const int b = blockIdx.x;
    const int t = threadIdx.x;  // 256
    if (t == 0) s_flags = 0;
    __syncthreads();
    {   // detection window: 256 words, in-bounds under byte/int32/int64 interps
        unsigned w = ((const unsigned*)maskp)[(b & 127) * 256 + t];
        int fl = (w > 1u) ? 1 : 0;
        if ((t & 1) && w != 0u) fl |= 2;
        if (fl) atomicOr(&s_flags, fl);
    }
    __syncthreads();
    const int fl = s_flags;
    const int md = (fl & 1) ? 0 : ((fl & 2) ? 1 : 2);

    const int row = b * 256 + t;
    bool pred;
    if (md == 0)      pred = ((const unsigned char*)maskp)[row] != 0;
    else if (md == 1) pred = ((const int*)maskp)[row] != 0;
    else              pred = ((const unsigned*)maskp)[2l * row] != 0;

    const int lane = t & 63;
    unsigned long long bal = __ballot(pred);
    int pre = __popcll(bal & ((1ull << lane) - 1ull));
    int cnt = __popcll(bal);
    int base = 0;
    if (lane == 0 && cnt) base = atomicAdd(&g_cnt[0], cnt);
    base = __shfl(base, 0);
    if (pred) g_rows[base + pre] = row;
    int base2 = 0;
    if (lane == 0 && cnt < 64) base2 = atomicAdd(&g_cnt[1], 64 - cnt);
    base2 = __shfl(base2, 0);
    if (!pred) g_rows[NROWS - 1 - (base2 + (lane - pre))] = row;
}

// ---------- fused: masked-row GEMM + unmasked-row copy ----------
__global__ __launch_bounds__(256, 3)
void main_kernel(const float* __restrict__ X, float* __restrict__ out) {
    __shared__ __attribute__((aligned(16))) float Abuf[2][128 * 64];  // fp32, chunk-swizzled
    __shared__ int rlist[128];

    const int bid = blockIdx.x;
    const int role = (bid >> 3) & 1;                // period-8: XCD-fair role mix
    const int idx8 = ((bid >> 4) << 3) | (bid & 7);
    const int t = threadIdx.x;
    const int lane = t & 63;

    if (role == 1) {
        // ---- copy role: 32 unmasked rows per block ----
        const int ncopy = g_cnt[1];
        if (idx8 * 32 >= ncopy) return;
        const int w = t >> 6;
#pragma unroll
        for (int i = 0; i < 8; i++) {
            int pos = idx8 * 32 + w * 8 + i;
            if (pos < ncopy) {
                const long r = g_rows[NROWS - 1 - pos];
                const float4* s = reinterpret_cast<const float4*>(X + r * DIMK);
                float4* d = reinterpret_cast<float4*>(out + r * DIMK);
                float4 v0 = s[lane], v1 = s[lane + 64];
                d[lane] = v0;
                d[lane + 64] = v1;
            }
        }
        return;
    }

    // ---- gemm role: 128 masked rows x 128 cols; XCD-lane owns whole row-panels ----
    const int lid = ((idx8 & 7) << 9) + (idx8 >> 3);
    const int tm = lid >> 2, tn = lid & 3;
    const int nmask = g_cnt[0];
    if (tm * 128 >= nmask) return;

    if (t < 128) {
        int pos = tm * 128 + t;
        rlist[t] = g_rows[pos < nmask ? pos : 0];
    }
    __syncthreads();

    const int wid = t >> 6, wr = wid >> 1, wc = wid & 1;
    const int l15 = lane & 15, lhi = lane >> 4;

    // staging: wave wid covers rows wid*32+i*4+(lane>>4), LDS chunk pos = lane&15;
    // position p of row r holds data chunk p^(r&15)  (read side XORs the same way)
    const int srow_base = wid * 32;
    const float* gsrc[8];
#pragma unroll
    for (int i = 0; i < 8; i++) {
        const int r = srow_base + i * 4 + (lane >> 4);
        const int c = (lane & 15) ^ (r & 15);
        gsrc[i] = X + (long)rlist[r] * DIMK + c * 4;
    }

    const unsigned short* bbase = g_Wt2 + (tn * 8 + wc * 4) * 8192 + lhi * 128 + l15 * 8;

    f32x4 acc[4][4] = {};
    bf16x8 bb[4][2];

    // prologue: issue A(0) then B(0); wait A only (B stays in flight)
#pragma unroll
    for (int i = 0; i < 8; i++)
        gload_lds16(gsrc[i], &Abuf[0][(srow_base + i * 4) * 64]);
    __builtin_amdgcn_sched_barrier(0);
#pragma unroll
    for (int n = 0; n < 4; n++)
#pragma unroll
        for (int s = 0; s < 2; s++)
            bb[n][s] = *reinterpret_cast<const bf16x8*>(bbase + n * 8192 + s * 512);
    __builtin_amdgcn_sched_barrier(0);
    asm volatile("s_waitcnt vmcnt(8)" ::: "memory");
    __builtin_amdgcn_s_barrier();

#pragma unroll
    for (int kt = 0; kt < 8; kt++) {
        __builtin_amdgcn_sched_barrier(0);
        if (kt < 7) {   // issue A(kt+1) into the other buffer (in flight across MFMA)
#pragma unroll
            for (int i = 0; i < 8; i++)
                gload_lds16(gsrc[i] + (kt + 1) * 64,
                            &Abuf[(kt + 1) & 1][(srow_base + i * 4) * 64]);
        }
        __builtin_amdgcn_sched_barrier(0);

        const float* Ab = Abuf[kt & 1];
        __builtin_amdgcn_s_setprio(1);
#pragma unroll
        for (int s = 0; s < 2; s++) {
#pragma unroll
            for (int m = 0; m < 4; m++) {
                const int row = wr * 64 + m * 16 + l15;
                const int c0 = s * 8 + lhi * 2;
                float4 lo = *reinterpret_cast<const float4*>(
                    &Ab[row * 64 + ((c0 ^ (row & 15)) << 2)]);
                float4 hi = *reinterpret_cast<const float4*>(
                    &Ab[row * 64 + (((c0 + 1) ^ (row & 15)) << 2)]);
                bf16x8 a;
                a[0] = (__bf16)lo.x; a[1] = (__bf16)lo.y;
                a[2] = (__bf16)lo.z; a[3] = (__bf16)lo.w;
                a[4] = (__bf16)hi.x; a[5] = (__bf16)hi.y;
                a[6] = (__bf16)hi.z; a[7] = (__bf16)hi.w;
#pragma unroll
                for (int n = 0; n < 4; n++)
                    acc[m][n] = __builtin_amdgcn_mfma_f32_16x16x32_bf16(
                        a, bb[n][s], acc[m][n], 0, 0, 0);
            }
        }
        __builtin_amdgcn_s_setprio(0);

        if (kt < 7) {
            __builtin_amdgcn_sched_barrier(0);
#pragma unroll
            for (int n = 0; n < 4; n++)
#pragma unroll
                for (int s = 0; s < 2; s++)
                    bb[n][s] = *reinterpret_cast<const bf16x8*>(
                        bbase + n * 8192 + (kt + 1) * 1024 + s * 512);
            __builtin_amdgcn_sched_barrier(0);
            // A(kt+1) done (8 oldest); B(kt+1) (8 youngest) stays in flight
            asm volatile("s_waitcnt vmcnt(8) lgkmcnt(0)" ::: "memory");
            __builtin_amdgcn_s_barrier();
        }
    }

    // epilogue: C/D col = l15, row = lhi*4 + j
    const int colb = tn * 128 + wc * 64;
#pragma unroll
    for (int m = 0; m < 4; m++) {
        const int rl_ = wr * 64 + m * 16 + lhi * 4;
#pragma unroll
        for (int j = 0; j < 4; j++) {
            const int pos = tm * 128 + rl_ + j;
            if (pos < nmask) {
                const long rg = rlist[rl_ + j];
                float* orow = out + rg * DIMK + colb;
#pragma unroll
                for (int n = 0; n < 4; n++)
                    orow[n * 16 + l15] = acc[m][n][j];
            }
        }
    }
}

extern "C" void kernel_launch(void* const* d_in, const int* in_sizes, int n_in,
                              void* d_out, int out_size, void* d_ws, size_t ws_size,
                              hipStream_t stream) {
    const float* X = (const float*)d_in[0];
    const void* mask = d_in[1];
    const float* W = (const float*)d_in[2];
    float* out = (float*)d_out;

    hipLaunchKernelGGL(wprep_kernel, dim3(64), dim3(256), 0, stream, W);
    hipLaunchKernelGGL(partition_kernel, dim3(NROWS / 256), dim3(256), 0, stream, mask);
    hipLaunchKernelGGL(main_kernel, dim3(8192), dim3(256), 0, stream, X, out);
}